// Round 3
// baseline (549.602 us; speedup 1.0000x reference)
//
#include <hip/hip_runtime.h>
#include <cstddef>

#define N_NODES_C 50000
#define N_EDGES_C 800000

typedef _Float16 f16x8 __attribute__((ext_vector_type(8)));
typedef float    f32x4 __attribute__((ext_vector_type(4)));

constexpr int XSTR  = 72;  // f16 stride for x/h LDS rows in kernel H
constexpr int HSTR  = 68;  // f32 stride for final-h LDS in kernel H

// ---------------------------------------------------------------------------
// Prep: wT[l][j][k] = W_l[k][j] (f16), and W3[(y*80+k)][x] f16:
//   k<64 -> w_out[k][y*64+x]; k==64 -> b_out[y*64+x]; k>64 -> 0.
// ---------------------------------------------------------------------------
__global__ void prep_kernel(const float* __restrict__ w_in,
                            const float* __restrict__ w_mid,
                            const float* __restrict__ w_out,
                            const float* __restrict__ b_out,
                            _Float16* __restrict__ wT,
                            _Float16* __restrict__ W3)
{
    const int idx = blockIdx.x * 256 + threadIdx.x;
    if (idx < 7 * 4096) {
        const int l = idx >> 12, rem = idx & 4095;
        const int j = rem >> 6, k = rem & 63;
        const float v = (l == 0) ? w_in[k * 64 + j]
                                 : w_mid[(size_t)(l - 1) * 4096 + k * 64 + j];
        wT[(size_t)l * 4096 + j * 64 + k] = (_Float16)v;
    } else {
        const int i2 = idx - 7 * 4096;
        if (i2 < 2560 * 64) {
            const int r = i2 >> 6, x = i2 & 63;
            const int y = r / 80;
            const int k = r - y * 80;
            float v = 0.f;
            if (k < 64)       v = w_out[(size_t)k * 2048 + y * 64 + x];
            else if (k == 64) v = b_out[y * 64 + x];
            W3[(size_t)r * 64 + x] = (_Float16)v;
        }
    }
}

// ---------------------------------------------------------------------------
// Kernel H: per-node MLP -> hF (f32, [N][64]). 64 nodes/block, 4 waves,
// wave w owns nodes [16w,16w+16). In-place f16 LDS ping within hb.
// ---------------------------------------------------------------------------
__launch_bounds__(256, 2)
__global__ void mlp_h_kernel(const float* __restrict__ xf,
                             const float* __restrict__ b_in,
                             const float* __restrict__ b_mid,
                             const _Float16* __restrict__ wT,
                             float* __restrict__ hF_g)
{
    __shared__ _Float16 xb[64 * XSTR];
    __shared__ _Float16 hb[64 * XSTR];
    __shared__ float    hFs[64 * HSTR];

    const int t    = threadIdx.x;
    const int w    = t >> 6;
    const int lane = t & 63;
    const int quad = lane >> 4;
    const int lrow = lane & 15;
    const int node0 = blockIdx.x * 64;

    // stage 0: x -> f16 LDS
    {
        const int n = t >> 2;
        const int nglob = min(node0 + n, N_NODES_C - 1);
        const float4* src = (const float4*)(xf + (size_t)nglob * 64);
        #pragma unroll
        for (int i = 0; i < 4; ++i) {
            const int x4 = (t & 3) + i * 4;
            const float4 v = src[x4];
            const int x = x4 * 4;
            xb[n * XSTR + x + 0] = (_Float16)v.x;
            xb[n * XSTR + x + 1] = (_Float16)v.y;
            xb[n * XSTR + x + 2] = (_Float16)v.z;
            xb[n * XSTR + x + 3] = (_Float16)v.w;
        }
    }
    __syncthreads();

    // stage 1: 7 layers
    const int myrow0 = w * 16;
    for (int l = 0; l < 7; ++l) {
        const _Float16* hsrc = (l == 0) ? xb : hb;
        const _Float16* wTl = wT + (size_t)l * 4096;
        const float* bsrc = (l == 0) ? b_in : (b_mid + (size_t)(l - 1) * 64);

        f16x8 B[4][2];
        float bias[4];
        #pragma unroll
        for (int Nt = 0; Nt < 4; ++Nt) {
            #pragma unroll
            for (int Ks = 0; Ks < 2; ++Ks)
                B[Nt][Ks] = *(const f16x8*)(wTl + (Nt * 16 + lrow) * 64 + Ks * 32 + quad * 8);
            bias[Nt] = bsrc[Nt * 16 + lrow];
        }
        const f16x8 A0 = *(const f16x8*)&hsrc[(myrow0 + lrow) * XSTR + quad * 8];
        const f16x8 A1 = *(const f16x8*)&hsrc[(myrow0 + lrow) * XSTR + 32 + quad * 8];

        #pragma unroll
        for (int Nt = 0; Nt < 4; ++Nt) {
            f32x4 C = {0.f, 0.f, 0.f, 0.f};
            C = __builtin_amdgcn_mfma_f32_16x16x32_f16(A0, B[Nt][0], C, 0, 0, 0);
            C = __builtin_amdgcn_mfma_f32_16x16x32_f16(A1, B[Nt][1], C, 0, 0, 0);
            const int j = Nt * 16 + lrow;
            #pragma unroll
            for (int r = 0; r < 4; ++r) {
                const int n = myrow0 + quad * 4 + r;
                float v = fmaxf(C[r] + bias[Nt], 0.f);
                if (l < 6) hb[n * XSTR + j] = (_Float16)v;
                else       hFs[n * HSTR + j] = v;
            }
        }
        __syncthreads();
    }

    // dump hFs -> global (coalesced)
    {
        const int n = t >> 2;
        const int c0 = (t & 3) * 16;
        const int ngl = node0 + n;
        if (ngl < N_NODES_C) {
            #pragma unroll
            for (int i = 0; i < 4; ++i) {
                const float4 v = *(const float4*)&hFs[n * HSTR + c0 + i * 4];
                *(float4*)(hF_g + (size_t)ngl * 64 + c0 + i * 4) = v;
            }
        }
    }
}

// ---------------------------------------------------------------------------
// Kernel Q: q[n, yt*8+y] = sum_k h[n,k] * (W3[y*80+k] . x[n]) (+bias row k=64),
// scaled by dinv[n]. Grid (98 chunks x 4 ytiles). W3 slice (80KB) in LDS,
// XOR-swizzled 16B chunks (2-way conflicts only). 2 node-groups (32 nodes)
// per wave iteration share the A-frags.
// ---------------------------------------------------------------------------
__launch_bounds__(256, 2)
__global__ void qcalc_kernel(const float* __restrict__ xf,
                             const float* __restrict__ hF,
                             const _Float16* __restrict__ W3,
                             const float* __restrict__ dinv,
                             float* __restrict__ qs)
{
    __shared__ _Float16 ws3[640 * 64];   // 80 KB

    const int t    = threadIdx.x;
    const int w    = t >> 6;
    const int lane = t & 63;
    const int quad = lane >> 4;
    const int lrow = lane & 15;
    const int yt   = blockIdx.y;
    const int cbase = blockIdx.x * 512;
    const int cend  = min(cbase + 512, N_NODES_C);

    // stage W3 slice, swizzled: logical (row r, 16B-chunk c) -> chunk c^(r&7)
    for (int i = t; i < 5120; i += 256) {
        const int r = i >> 3, c = i & 7;
        const f16x8 v = *(const f16x8*)(W3 + ((size_t)(yt * 640 + r)) * 64 + c * 8);
        *(f16x8*)(ws3 + r * 64 + ((c ^ (r & 7)) * 8)) = v;
    }
    __syncthreads();

    const int sw = lrow & 7;                 // r&7 == lrow&7 for all (y,Mt)
    const int o0 = ((quad     ^ sw) * 8);    // f16 offset of A0 chunk
    const int o1 = (((quad + 4) ^ sw) * 8);  // f16 offset of A1 chunk

    for (int p0 = cbase + w * 32; p0 < cend; p0 += 128) {
        const int n1v = p0 + 16;
        const bool v1 = (n1v < cend);
        const int na = p0 + lrow;
        const int nb = v1 ? (n1v + lrow) : na;

        // x -> f16 B-frags
        f16x8 BX[2][2];
        {
            const float4* pa = (const float4*)(xf + (size_t)na * 64);
            const float4* pb = (const float4*)(xf + (size_t)nb * 64);
            #pragma unroll
            for (int ks = 0; ks < 2; ++ks) {
                const float4 a0 = pa[ks * 8 + quad * 2];
                const float4 a1 = pa[ks * 8 + quad * 2 + 1];
                BX[0][ks] = (f16x8){(_Float16)a0.x, (_Float16)a0.y, (_Float16)a0.z, (_Float16)a0.w,
                                    (_Float16)a1.x, (_Float16)a1.y, (_Float16)a1.z, (_Float16)a1.w};
                const float4 b0 = pb[ks * 8 + quad * 2];
                const float4 b1 = pb[ks * 8 + quad * 2 + 1];
                BX[1][ks] = (f16x8){(_Float16)b0.x, (_Float16)b0.y, (_Float16)b0.z, (_Float16)b0.w,
                                    (_Float16)b1.x, (_Float16)b1.y, (_Float16)b1.z, (_Float16)b1.w};
            }
        }
        // h fragments (C-layout aligned: k = Mt*16 + quad*4 + r)
        float4 hr[2][4];
        #pragma unroll
        for (int Mt = 0; Mt < 4; ++Mt) {
            hr[0][Mt] = *(const float4*)(hF + (size_t)na * 64 + Mt * 16 + quad * 4);
            hr[1][Mt] = *(const float4*)(hF + (size_t)nb * 64 + Mt * 16 + quad * 4);
        }
        const float dva = dinv[na];
        const float dvb = dinv[nb];

        float qva[8], qvb[8];
        #pragma unroll
        for (int y = 0; y < 8; ++y) {
            float qa = 0.f, qb = 0.f;
            #pragma unroll
            for (int Mt = 0; Mt < 5; ++Mt) {
                const int r = y * 80 + Mt * 16 + lrow;
                const f16x8 A0 = *(const f16x8*)(ws3 + r * 64 + o0);
                const f16x8 A1 = *(const f16x8*)(ws3 + r * 64 + o1);
                f32x4 C0 = {0.f, 0.f, 0.f, 0.f};
                C0 = __builtin_amdgcn_mfma_f32_16x16x32_f16(A0, BX[0][0], C0, 0, 0, 0);
                C0 = __builtin_amdgcn_mfma_f32_16x16x32_f16(A1, BX[0][1], C0, 0, 0, 0);
                f32x4 C1 = {0.f, 0.f, 0.f, 0.f};
                C1 = __builtin_amdgcn_mfma_f32_16x16x32_f16(A0, BX[1][0], C1, 0, 0, 0);
                C1 = __builtin_amdgcn_mfma_f32_16x16x32_f16(A1, BX[1][1], C1, 0, 0, 0);
                if (Mt < 4) {
                    const float4 ha = hr[0][Mt];
                    qa += C0[0] * ha.x + C0[1] * ha.y + C0[2] * ha.z + C0[3] * ha.w;
                    const float4 hbv = hr[1][Mt];
                    qb += C1[0] * hbv.x + C1[1] * hbv.y + C1[2] * hbv.z + C1[3] * hbv.w;
                } else if (quad == 0) {   // bias row k==64 (rows 65..79 are zero)
                    qa += C0[0];
                    qb += C1[0];
                }
            }
            qa += __shfl_xor(qa, 16);
            qa += __shfl_xor(qa, 32);
            qb += __shfl_xor(qb, 16);
            qb += __shfl_xor(qb, 32);
            qva[y] = qa;
            qvb[y] = qb;
        }

        float* qpa = qs + (size_t)na * 32 + yt * 8;
        if (quad == 0)
            *(float4*)qpa = make_float4(qva[0] * dva, qva[1] * dva, qva[2] * dva, qva[3] * dva);
        if (quad == 1)
            *(float4*)(qpa + 4) = make_float4(qva[4] * dva, qva[5] * dva, qva[6] * dva, qva[7] * dva);
        if (v1) {
            float* qpb = qs + (size_t)nb * 32 + yt * 8;
            if (quad == 2)
                *(float4*)qpb = make_float4(qvb[0] * dvb, qvb[1] * dvb, qvb[2] * dvb, qvb[3] * dvb);
            if (quad == 3)
                *(float4*)(qpb + 4) = make_float4(qvb[4] * dvb, qvb[5] * dvb, qvb[6] * dvb, qvb[7] * dvb);
        }
    }
}

// ---------------------------------------------------------------------------
// Edge pipeline: deg -> dinv -> scan -> fill (counting sort) -> gather
// ---------------------------------------------------------------------------
__global__ void deg_kernel(const int* __restrict__ col, int* __restrict__ deg)
{
    const int e = blockIdx.x * 256 + threadIdx.x;
    if (e < N_EDGES_C) atomicAdd(&deg[col[e]], 1);
}

__global__ void dinv_kernel(const int* __restrict__ deg, float* __restrict__ dinv)
{
    const int i = blockIdx.x * 256 + threadIdx.x;
    if (i < N_NODES_C) {
        const int d = deg[i];
        dinv[i] = (d > 0) ? rsqrtf((float)d) : 0.f;
    }
}

__global__ void scan_kernel(const int* __restrict__ deg,
                            int* __restrict__ rowptr,
                            int* __restrict__ pos)
{
    __shared__ int part[1024];
    const int t = threadIdx.x;
    const int base = t * 49;
    int s = 0;
    for (int i = 0; i < 49; ++i) {
        const int idx = base + i;
        if (idx < N_NODES_C) s += deg[idx];
    }
    part[t] = s;
    __syncthreads();
    for (int off = 1; off < 1024; off <<= 1) {
        const int v = (t >= off) ? part[t - off] : 0;
        __syncthreads();
        part[t] += v;
        __syncthreads();
    }
    int run = part[t] - s;   // exclusive prefix
    for (int i = 0; i < 49; ++i) {
        const int idx = base + i;
        if (idx < N_NODES_C) {
            rowptr[idx] = run;
            pos[idx] = run;
            run += deg[idx];
        }
    }
    if (t == 0) rowptr[N_NODES_C] = N_EDGES_C;
}

__global__ void fill_kernel(const int* __restrict__ row, const int* __restrict__ col,
                            int* __restrict__ pos, int* __restrict__ src)
{
    const int e = blockIdx.x * 256 + threadIdx.x;
    if (e < N_EDGES_C) {
        const int slot = atomicAdd(&pos[col[e]], 1);
        src[slot] = row[e];
    }
}

__global__ void gather_kernel(const int* __restrict__ rowptr, const int* __restrict__ src,
                              const float* __restrict__ qs, const float* __restrict__ dinv,
                              float* __restrict__ out)
{
    const int t = threadIdx.x;
    const int node = blockIdx.x * 8 + (t >> 5);
    const int y = t & 31;
    const int s0 = rowptr[node];
    const int s1 = rowptr[node + 1];
    float acc = 0.f;
    int s = s0;
    for (; s + 2 <= s1; s += 2) {
        const int r0 = src[s];
        const int r1 = src[s + 1];
        acc += qs[(size_t)r0 * 32 + y];
        acc += qs[(size_t)r1 * 32 + y];
    }
    if (s < s1) acc += qs[(size_t)src[s] * 32 + y];
    out[(size_t)node * 32 + y] = acc * dinv[node];
}

// ---------------------------------------------------------------------------
extern "C" void kernel_launch(void* const* d_in, const int* in_sizes, int n_in,
                              void* d_out, int out_size, void* d_ws, size_t ws_size,
                              hipStream_t stream)
{
    const float* xf    = (const float*)d_in[0];
    const int*   eidx  = (const int*)d_in[1];
    const float* w_in  = (const float*)d_in[2];
    const float* b_in  = (const float*)d_in[3];
    const float* w_mid = (const float*)d_in[4];
    const float* b_mid = (const float*)d_in[5];
    const float* w_out = (const float*)d_in[6];
    const float* b_out = (const float*)d_in[7];
    float* out = (float*)d_out;

    const int* row = eidx;
    const int* col = eidx + N_EDGES_C;

    // workspace layout (bytes); CSR buffers alias hF (dead after qcalc)
    char* ws = (char*)d_ws;
    float*    qs   = (float*)(ws + 0);           //  6,400,000
    int*      deg  = (int*)(ws + 6400000);       //    200,000
    float*    dinv = (float*)(ws + 6600000);     //    200,000
    _Float16* wT   = (_Float16*)(ws + 6800000);  //     57,344
    _Float16* W3   = (_Float16*)(ws + 6857344);  //    327,680
    float*    hF   = (float*)(ws + 7185024);     // 12,800,000  -> total 19,985,024
    int*      rowptr = (int*)(ws + 7185024);     // alias (200,004)
    int*      pos    = (int*)(ws + 7385040);     // alias (200,000)
    int*      srcb   = (int*)(ws + 7585040);     // alias (3,200,000)

    hipMemsetAsync(deg, 0, N_NODES_C * sizeof(int), stream);

    prep_kernel<<<dim3(752), dim3(256), 0, stream>>>(w_in, w_mid, w_out, b_out, wT, W3);

    deg_kernel<<<dim3((N_EDGES_C + 255) / 256), dim3(256), 0, stream>>>(col, deg);
    dinv_kernel<<<dim3((N_NODES_C + 255) / 256), dim3(256), 0, stream>>>(deg, dinv);

    mlp_h_kernel<<<dim3((N_NODES_C + 63) / 64), dim3(256), 0, stream>>>(
        xf, b_in, b_mid, wT, hF);

    qcalc_kernel<<<dim3(98, 4), dim3(256), 0, stream>>>(xf, hF, W3, dinv, qs);

    // hF dead from here on; CSR aliases become live
    scan_kernel<<<dim3(1), dim3(1024), 0, stream>>>(deg, rowptr, pos);
    fill_kernel<<<dim3((N_EDGES_C + 255) / 256), dim3(256), 0, stream>>>(row, col, pos, srcb);
    gather_kernel<<<dim3(N_NODES_C / 8), dim3(256), 0, stream>>>(rowptr, srcb, qs, dinv, out);
}

// Round 4
// 271.326 us; speedup vs baseline: 2.0256x; 2.0256x over previous
//
#include <hip/hip_runtime.h>
#include <cstddef>

#define N_NODES_C 50000
#define N_EDGES_C 800000

typedef _Float16 f16x8 __attribute__((ext_vector_type(8)));
typedef float    f32x4 __attribute__((ext_vector_type(4)));

constexpr int XSTR = 72;  // f16 stride for x/h LDS rows in kernel H
constexpr int HSTR = 68;  // f32 stride for final-h LDS in kernel H

// ---------------------------------------------------------------------------
// Prep:
//  wT[l][j][k] = W_l[k][j] (f16)  — for mlp_h B-frags
//  W3T[r= y*64+x][64 k] (f16), 16B chunks XOR-swizzled: chunk c of row r is
//  stored at chunk position c^(r&7). Value = w_out[k*2048 + r].
// ---------------------------------------------------------------------------
__global__ void prep_kernel(const float* __restrict__ w_in,
                            const float* __restrict__ w_mid,
                            const float* __restrict__ w_out,
                            _Float16* __restrict__ wT,
                            _Float16* __restrict__ W3T)
{
    const int idx = blockIdx.x * 256 + threadIdx.x;
    if (idx < 7 * 4096) {
        const int l = idx >> 12, rem = idx & 4095;
        const int j = rem >> 6, k = rem & 63;
        const float v = (l == 0) ? w_in[k * 64 + j]
                                 : w_mid[(size_t)(l - 1) * 4096 + k * 64 + j];
        wT[(size_t)l * 4096 + j * 64 + k] = (_Float16)v;
    } else {
        const int i2 = idx - 7 * 4096;   // < 131072
        const int r = i2 >> 6, k = i2 & 63;
        const int c = k >> 3;
        const int pos = ((c ^ (r & 7)) << 3) | (k & 7);
        W3T[(size_t)r * 64 + pos] = (_Float16)w_out[(size_t)k * 2048 + r];
    }
}

// ---------------------------------------------------------------------------
// Kernel H: per-node MLP -> hG (f16, [N][64]). 64 nodes/block, 4 waves.
// ---------------------------------------------------------------------------
__launch_bounds__(256, 2)
__global__ void mlp_h_kernel(const float* __restrict__ xf,
                             const float* __restrict__ b_in,
                             const float* __restrict__ b_mid,
                             const _Float16* __restrict__ wT,
                             _Float16* __restrict__ hG)
{
    __shared__ _Float16 xb[64 * XSTR];
    __shared__ _Float16 hb[64 * XSTR];
    __shared__ float    hFs[64 * HSTR];

    const int t    = threadIdx.x;
    const int w    = t >> 6;
    const int lane = t & 63;
    const int quad = lane >> 4;
    const int lrow = lane & 15;
    const int node0 = blockIdx.x * 64;

    // stage 0: x -> f16 LDS
    {
        const int n = t >> 2;
        const int nglob = min(node0 + n, N_NODES_C - 1);
        const float4* src = (const float4*)(xf + (size_t)nglob * 64);
        #pragma unroll
        for (int i = 0; i < 4; ++i) {
            const int x4 = (t & 3) + i * 4;
            const float4 v = src[x4];
            const int x = x4 * 4;
            xb[n * XSTR + x + 0] = (_Float16)v.x;
            xb[n * XSTR + x + 1] = (_Float16)v.y;
            xb[n * XSTR + x + 2] = (_Float16)v.z;
            xb[n * XSTR + x + 3] = (_Float16)v.w;
        }
    }
    __syncthreads();

    // 7 layers
    const int myrow0 = w * 16;
    for (int l = 0; l < 7; ++l) {
        const _Float16* hsrc = (l == 0) ? xb : hb;
        const _Float16* wTl = wT + (size_t)l * 4096;
        const float* bsrc = (l == 0) ? b_in : (b_mid + (size_t)(l - 1) * 64);

        f16x8 B[4][2];
        float bias[4];
        #pragma unroll
        for (int Nt = 0; Nt < 4; ++Nt) {
            #pragma unroll
            for (int Ks = 0; Ks < 2; ++Ks)
                B[Nt][Ks] = *(const f16x8*)(wTl + (Nt * 16 + lrow) * 64 + Ks * 32 + quad * 8);
            bias[Nt] = bsrc[Nt * 16 + lrow];
        }
        const f16x8 A0 = *(const f16x8*)&hsrc[(myrow0 + lrow) * XSTR + quad * 8];
        const f16x8 A1 = *(const f16x8*)&hsrc[(myrow0 + lrow) * XSTR + 32 + quad * 8];

        #pragma unroll
        for (int Nt = 0; Nt < 4; ++Nt) {
            f32x4 C = {0.f, 0.f, 0.f, 0.f};
            C = __builtin_amdgcn_mfma_f32_16x16x32_f16(A0, B[Nt][0], C, 0, 0, 0);
            C = __builtin_amdgcn_mfma_f32_16x16x32_f16(A1, B[Nt][1], C, 0, 0, 0);
            const int j = Nt * 16 + lrow;
            #pragma unroll
            for (int r = 0; r < 4; ++r) {
                const int n = myrow0 + quad * 4 + r;
                float v = fmaxf(C[r] + bias[Nt], 0.f);
                if (l < 6) hb[n * XSTR + j] = (_Float16)v;
                else       hFs[n * HSTR + j] = v;
            }
        }
        __syncthreads();
    }

    // dump -> f16 global (coalesced)
    {
        const int n = t >> 2;
        const int c0 = (t & 3) * 16;
        const int ngl = node0 + n;
        if (ngl < N_NODES_C) {
            _Float16 tmp[16];
            #pragma unroll
            for (int i = 0; i < 16; ++i) tmp[i] = (_Float16)hFs[n * HSTR + c0 + i];
            *(f16x8*)(hG + (size_t)ngl * 64 + c0)     = *(f16x8*)&tmp[0];
            *(f16x8*)(hG + (size_t)ngl * 64 + c0 + 8) = *(f16x8*)&tmp[8];
        }
    }
}

// ---------------------------------------------------------------------------
// Kernel Q: q[n,y] = dinv[n] * sum_x (sum_k h[n,k] W3[y,k,x] + b_out[y,x]) x[n,x]
// Block = 256 threads (4 waves), 128 nodes/block, 32 nodes/wave (2 groups).
// Per y: A = W3T_y slice from double-buffered LDS (8 ds_read_b128 shared by
// 16 MFMAs), C has node on cols -> per-lane dot with x + 2 shfl-xor.
// ---------------------------------------------------------------------------
__launch_bounds__(256, 3)
__global__ void qcalc_kernel(const float* __restrict__ xf,
                             const _Float16* __restrict__ hG,
                             const _Float16* __restrict__ W3T,
                             const float* __restrict__ b_out,
                             const float* __restrict__ dinv,
                             float* __restrict__ qs)
{
    __shared__ _Float16 ws3[2][4096];   // 2 x 8 KB

    const int t    = threadIdx.x;
    const int w    = t >> 6;
    const int lane = t & 63;
    const int quad = lane >> 4;
    const int lrow = lane & 15;

    const int base = blockIdx.x * 128 + w * 32;
    const int ra = base + lrow;
    const int rb = base + 16 + lrow;
    const int na = min(ra, N_NODES_C - 1);
    const int nb = min(rb, N_NODES_C - 1);

    // hoisted B-frags (h, f16) and x C-pattern frags (f32)
    f16x8 Bha[2], Bhb[2];
    #pragma unroll
    for (int ks = 0; ks < 2; ++ks) {
        Bha[ks] = *(const f16x8*)(hG + (size_t)na * 64 + ks * 32 + quad * 8);
        Bhb[ks] = *(const f16x8*)(hG + (size_t)nb * 64 + ks * 32 + quad * 8);
    }
    float4 xca[4], xcb[4];
    #pragma unroll
    for (int xt = 0; xt < 4; ++xt) {
        xca[xt] = *(const float4*)(xf + (size_t)na * 64 + xt * 16 + quad * 4);
        xcb[xt] = *(const float4*)(xf + (size_t)nb * 64 + xt * 16 + quad * 4);
    }
    const float dva = dinv[na];
    const float dvb = dinv[nb];

    // prefetch y=0 slice (dense copy preserves the global-side swizzle)
    {
        const f16x8 v0 = *(const f16x8*)(W3T + (size_t)t * 8);
        const f16x8 v1 = *(const f16x8*)(W3T + (size_t)(t + 256) * 8);
        *(f16x8*)(&ws3[0][t * 8]) = v0;
        *(f16x8*)(&ws3[0][(t + 256) * 8]) = v1;
    }

    const int swz = lrow & 7;
    const int cp0 = ((quad)     ^ swz) * 8;   // ks=0 chunk offset (f16)
    const int cp1 = ((4 + quad) ^ swz) * 8;   // ks=1 chunk offset

    __syncthreads();

    for (int y = 0; y < 32; ++y) {
        // issue next slice's global loads early (lands during compute)
        f16x8 nv0, nv1;
        if (y + 1 < 32) {
            nv0 = *(const f16x8*)(W3T + (size_t)(y + 1) * 4096 + t * 8);
            nv1 = *(const f16x8*)(W3T + (size_t)(y + 1) * 4096 + (t + 256) * 8);
        }

        const _Float16* cur = ws3[y & 1];
        float qa = 0.f, qb = 0.f;
        #pragma unroll
        for (int xt = 0; xt < 4; ++xt) {
            const _Float16* rp = cur + (xt * 16 + lrow) * 64;
            const f16x8 A0 = *(const f16x8*)(rp + cp0);
            const f16x8 A1 = *(const f16x8*)(rp + cp1);
            f32x4 Ca = {0.f, 0.f, 0.f, 0.f};
            Ca = __builtin_amdgcn_mfma_f32_16x16x32_f16(A0, Bha[0], Ca, 0, 0, 0);
            Ca = __builtin_amdgcn_mfma_f32_16x16x32_f16(A1, Bha[1], Ca, 0, 0, 0);
            f32x4 Cb = {0.f, 0.f, 0.f, 0.f};
            Cb = __builtin_amdgcn_mfma_f32_16x16x32_f16(A0, Bhb[0], Cb, 0, 0, 0);
            Cb = __builtin_amdgcn_mfma_f32_16x16x32_f16(A1, Bhb[1], Cb, 0, 0, 0);

            const float4 bf = *(const float4*)(b_out + y * 64 + xt * 16 + quad * 4);
            qa += (Ca[0] + bf.x) * xca[xt].x + (Ca[1] + bf.y) * xca[xt].y
                + (Ca[2] + bf.z) * xca[xt].z + (Ca[3] + bf.w) * xca[xt].w;
            qb += (Cb[0] + bf.x) * xcb[xt].x + (Cb[1] + bf.y) * xcb[xt].y
                + (Cb[2] + bf.z) * xcb[xt].z + (Cb[3] + bf.w) * xcb[xt].w;
        }
        qa += __shfl_xor(qa, 16);
        qa += __shfl_xor(qa, 32);
        qb += __shfl_xor(qb, 16);
        qb += __shfl_xor(qb, 32);

        if (quad == (y >> 3)) {               // quad q stores y in [8q, 8q+8)
            if (ra < N_NODES_C) qs[(size_t)ra * 32 + y] = qa * dva;
            if (rb < N_NODES_C) qs[(size_t)rb * 32 + y] = qb * dvb;
        }

        if (y + 1 < 32) {
            _Float16* nxt = ws3[(y + 1) & 1];
            *(f16x8*)(&nxt[t * 8]) = nv0;
            *(f16x8*)(&nxt[(t + 256) * 8]) = nv1;
        }
        __syncthreads();
    }
}

// ---------------------------------------------------------------------------
// Edge pipeline: deg -> dinv -> 3-phase scan -> fill -> gather
// ---------------------------------------------------------------------------
__global__ void deg_kernel(const int* __restrict__ col, int* __restrict__ deg)
{
    const int e = blockIdx.x * 256 + threadIdx.x;
    if (e < N_EDGES_C) atomicAdd(&deg[col[e]], 1);
}

__global__ void dinv_kernel(const int* __restrict__ deg, float* __restrict__ dinv)
{
    const int i = blockIdx.x * 256 + threadIdx.x;
    if (i < N_NODES_C) {
        const int d = deg[i];
        dinv[i] = (d > 0) ? rsqrtf((float)d) : 0.f;
    }
}

__global__ void scan1_kernel(const int* __restrict__ deg, int* __restrict__ bsum)
{
    const int t = threadIdx.x;
    const int i = blockIdx.x * 256 + t;
    int v = (i < N_NODES_C) ? deg[i] : 0;
    #pragma unroll
    for (int d = 1; d < 64; d <<= 1) v += __shfl_xor(v, d);
    __shared__ int s[4];
    if ((t & 63) == 0) s[t >> 6] = v;
    __syncthreads();
    if (t == 0) bsum[blockIdx.x] = s[0] + s[1] + s[2] + s[3];
}

__global__ void scan2_kernel(const int* __restrict__ bsum, int* __restrict__ boff,
                             int* __restrict__ rowptr)
{
    __shared__ int sh[256];
    const int t = threadIdx.x;
    const int v = (t < 196) ? bsum[t] : 0;
    sh[t] = v;
    __syncthreads();
    for (int d = 1; d < 256; d <<= 1) {
        const int u = (t >= d) ? sh[t - d] : 0;
        __syncthreads();
        sh[t] += u;
        __syncthreads();
    }
    if (t < 196) boff[t] = sh[t] - v;     // exclusive
    if (t == 0) rowptr[N_NODES_C] = N_EDGES_C;
}

__global__ void scan3_kernel(const int* __restrict__ deg, const int* __restrict__ boff,
                             int* __restrict__ rowptr, int* __restrict__ pos)
{
    const int t = threadIdx.x;
    const int i = blockIdx.x * 256 + t;
    const int lane = t & 63, w = t >> 6;
    const int v = (i < N_NODES_C) ? deg[i] : 0;
    int inc = v;
    #pragma unroll
    for (int d = 1; d < 64; d <<= 1) {
        const int u = __shfl_up(inc, d);
        if (lane >= d) inc += u;
    }
    __shared__ int ws[4];
    if (lane == 63) ws[w] = inc;
    __syncthreads();
    int wo = 0;
    #pragma unroll
    for (int k = 0; k < 4; ++k) if (k < w) wo += ws[k];
    const int excl = boff[blockIdx.x] + wo + inc - v;
    if (i < N_NODES_C) {
        rowptr[i] = excl;
        pos[i] = excl;
    }
}

__global__ void fill_kernel(const int* __restrict__ row, const int* __restrict__ col,
                            int* __restrict__ pos, int* __restrict__ src)
{
    const int e = blockIdx.x * 256 + threadIdx.x;
    if (e < N_EDGES_C) {
        const int slot = atomicAdd(&pos[col[e]], 1);
        src[slot] = row[e];
    }
}

__global__ void gather_kernel(const int* __restrict__ rowptr, const int* __restrict__ src,
                              const float* __restrict__ qs, const float* __restrict__ dinv,
                              float* __restrict__ out)
{
    const int t = threadIdx.x;
    const int node = blockIdx.x * 8 + (t >> 5);
    const int y = t & 31;
    const int s0 = rowptr[node];
    const int s1 = rowptr[node + 1];
    float acc = 0.f;
    int s = s0;
    for (; s + 4 <= s1; s += 4) {
        const int r0 = src[s], r1 = src[s + 1], r2 = src[s + 2], r3 = src[s + 3];
        acc += qs[(size_t)r0 * 32 + y];
        acc += qs[(size_t)r1 * 32 + y];
        acc += qs[(size_t)r2 * 32 + y];
        acc += qs[(size_t)r3 * 32 + y];
    }
    for (; s < s1; ++s) acc += qs[(size_t)src[s] * 32 + y];
    out[(size_t)node * 32 + y] = acc * dinv[node];
}

// ---------------------------------------------------------------------------
extern "C" void kernel_launch(void* const* d_in, const int* in_sizes, int n_in,
                              void* d_out, int out_size, void* d_ws, size_t ws_size,
                              hipStream_t stream)
{
    const float* xf    = (const float*)d_in[0];
    const int*   eidx  = (const int*)d_in[1];
    const float* w_in  = (const float*)d_in[2];
    const float* b_in  = (const float*)d_in[3];
    const float* w_mid = (const float*)d_in[4];
    const float* b_mid = (const float*)d_in[5];
    const float* w_out = (const float*)d_in[6];
    const float* b_out = (const float*)d_in[7];
    float* out = (float*)d_out;

    const int* row = eidx;
    const int* col = eidx + N_EDGES_C;

    // workspace layout (bytes)
    char* ws = (char*)d_ws;
    float*    qs     = (float*)(ws + 0);            //  6,400,000
    int*      deg    = (int*)(ws + 6400000);        //    200,000
    float*    dinv   = (float*)(ws + 6600000);      //    200,000
    _Float16* wT     = (_Float16*)(ws + 6800000);   //     57,344
    _Float16* W3T    = (_Float16*)(ws + 6857344);   //    262,144
    _Float16* hG     = (_Float16*)(ws + 7119488);   //  6,400,000
    int*      rowptr = (int*)(ws + 13519488);       //    200,004
    int*      pos    = (int*)(ws + 13719492);       //    200,000
    int*      srcb   = (int*)(ws + 13919492);       //  3,200,000
    int*      bsum   = (int*)(ws + 17119492);       //        784
    int*      boff   = (int*)(ws + 17120276);       //        784

    hipMemsetAsync(deg, 0, N_NODES_C * sizeof(int), stream);

    prep_kernel<<<dim3(624), dim3(256), 0, stream>>>(w_in, w_mid, w_out, wT, W3T);

    deg_kernel<<<dim3((N_EDGES_C + 255) / 256), dim3(256), 0, stream>>>(col, deg);
    dinv_kernel<<<dim3((N_NODES_C + 255) / 256), dim3(256), 0, stream>>>(deg, dinv);

    mlp_h_kernel<<<dim3((N_NODES_C + 63) / 64), dim3(256), 0, stream>>>(
        xf, b_in, b_mid, wT, hG);

    qcalc_kernel<<<dim3((N_NODES_C + 127) / 128), dim3(256), 0, stream>>>(
        xf, hG, W3T, b_out, dinv, qs);

    scan1_kernel<<<dim3(196), dim3(256), 0, stream>>>(deg, bsum);
    scan2_kernel<<<dim3(1), dim3(256), 0, stream>>>(bsum, boff, rowptr);
    scan3_kernel<<<dim3(196), dim3(256), 0, stream>>>(deg, boff, rowptr, pos);
    fill_kernel<<<dim3((N_EDGES_C + 255) / 256), dim3(256), 0, stream>>>(row, col, pos, srcb);
    gather_kernel<<<dim3(N_NODES_C / 8), dim3(256), 0, stream>>>(rowptr, srcb, qs, dinv, out);
}